// Round 3
// baseline (4260.790 us; speedup 1.0000x reference)
//
#include <hip/hip_runtime.h>
#include <math.h>

// Problem constants
#define NB   16
#define CC   256
#define NPTS 16384       // 16*32*32
#define KK   8192
#define Z_OUT 4194304    // NPTS*CC
// d_out: [0,Z_OUT) z_q_out (BCHW), [Z_OUT,Z_OUT+NPTS) idx as float, [Z_OUT+NPTS] loss

// ws layout (floats)
#define WS_ZNORM 64
#define WS_ENORM 16448
#define WS_ET    32768   // eT[c][k], 8 MB

__device__ __forceinline__ void gl_lds16(const float* g, float* l) {
    __builtin_amdgcn_global_load_lds((const __attribute__((address_space(1))) void*)g,
                                     (__attribute__((address_space(3))) void*)l, 16, 0, 0);
}

// ---------------- K0a: znorm + zero loss accumulator ----------------
__global__ void k_znorm(const float* __restrict__ z, float* __restrict__ znorm,
                        float* __restrict__ lossAcc) {
    const int n  = blockIdx.x * 256 + threadIdx.x;
    const int b  = n >> 10, hw = n & 1023;
    const float* p = z + (size_t)b * 262144 + hw;
    float s = 0.0f;
#pragma unroll 8
    for (int c = 0; c < CC; ++c) {
        float v = p[(size_t)c * 1024];
        s = fmaf(v, v, s);
    }
    znorm[n] = s;
    if (n == 0) lossAcc[0] = 0.0f;
}

// ---------------- K0b: transpose emb[k][c] -> eT[c][k] ----------------
__global__ void k_transpose(const float* __restrict__ emb, float* __restrict__ eT) {
    __shared__ float ts[64][65];
    const int k0 = blockIdx.x * 64;
    const int c0 = blockIdx.y * 64;
    const int tid = threadIdx.x;
#pragma unroll
    for (int p = 0; p < 4; ++p) {
        int u = p * 256 + tid;
        int i = u >> 4, j4 = (u & 15) << 2;
        float4 v = *(const float4*)(emb + (size_t)(k0 + i) * CC + c0 + j4);
        ts[i][j4 + 0] = v.x; ts[i][j4 + 1] = v.y; ts[i][j4 + 2] = v.z; ts[i][j4 + 3] = v.w;
    }
    __syncthreads();
#pragma unroll
    for (int p = 0; p < 4; ++p) {
        int u = p * 256 + tid;
        int j = u >> 4, i4 = (u & 15) << 2;
        float4 v = make_float4(ts[i4 + 0][j], ts[i4 + 1][j], ts[i4 + 2][j], ts[i4 + 3][j]);
        *(float4*)(eT + (size_t)(c0 + j) * KK + k0 + i4) = v;
    }
}

// ---------------- K0c: enorm ----------------
__global__ void k_enorm(const float* __restrict__ emb, float* __restrict__ enorm) {
    const int w = threadIdx.x >> 6, lane = threadIdx.x & 63;
    const int k = blockIdx.x * 4 + w;
    float4 v = *(const float4*)(emb + (size_t)k * CC + lane * 4);
    float s = v.x * v.x + v.y * v.y + v.z * v.z + v.w * v.w;
    for (int off = 32; off > 0; off >>= 1) s += __shfl_down(s, off);
    if (lane == 0) enorm[k] = s;
}

// ---------------- K1: fused GEMM-distance + argmin ----------------
// 256 blocks x 512 threads (8 waves, pinned 2 waves/EU -> 256 VGPR budget).
// Block = 64 n; thread tile 8n x 16k; c-chunks of 16, double-buffered LDS.
// es layout (per buf): c*1024 + q*256 + lane*4 + r  <->  k = lane*16 + q*4 + r
// zs layout (per buf): c*64 + m
#define ES_BUF 16384   // floats per es buffer
#define ZS_BUF 1024    // floats per zs buffer

__global__ __attribute__((amdgpu_flat_work_group_size(512, 512), amdgpu_waves_per_eu(2, 2)))
void k_argmin(const float* __restrict__ z, const float* __restrict__ eT,
              const float* __restrict__ znorm, const float* __restrict__ enorm,
              float* __restrict__ idx_out) {
    __shared__ float es[2 * ES_BUF];   // 128 KB
    __shared__ float zs[2 * ZS_BUF];   // 8 KB
    const int tid  = threadIdx.x;
    const int lane = tid & 63;
    const int w    = tid >> 6;         // wave 0..7
    const int kg   = tid >> 3;         // 0..63 (16 k's each)
    const int ng   = tid & 7;          // 0..7  (8 n's each)
    const int nb   = blockIdx.x << 6;
    const float* zbase = z + (size_t)(nb >> 10) * 262144 + (nb & 1023);

    // thread's 8 znorm values
    float zn[8];
    {
        float4 a = *(const float4*)(znorm + nb + ng * 8);
        float4 b = *(const float4*)(znorm + nb + ng * 8 + 4);
        zn[0]=a.x; zn[1]=a.y; zn[2]=a.z; zn[3]=a.w; zn[4]=b.x; zn[5]=b.y; zn[6]=b.z; zn[7]=b.w;
    }

    float bv[8]; int bi[8];
#pragma unroll
    for (int i = 0; i < 8; ++i) { bv[i] = __builtin_inff(); bi[i] = 0; }

    // stage chunk t into buf t&1
    auto stage = [&](int t) {
        const int pass = t >> 4, chunk = t & 15;
        const int c0 = chunk * 16, k0 = pass * 1024;
        float* esb = es + (size_t)(t & 1) * ES_BUF;
        float* zsb = zs + (size_t)(t & 1) * ZS_BUF;
        // e: wave w stages local c rows 2w, 2w+1 (4 q-loads each)
#pragma unroll
        for (int r = 0; r < 2; ++r) {
            const int c = 2 * w + r;
            const float* grow = eT + (size_t)(c0 + c) * KK + k0 + lane * 16;
            float* lb = esb + c * 1024;
            gl_lds16(grow + 0,  lb + 0);
            gl_lds16(grow + 4,  lb + 256);
            gl_lds16(grow + 8,  lb + 512);
            gl_lds16(grow + 12, lb + 768);
        }
        // z: waves 0..3, 4 c-rows each (64 consecutive n, 4 floats/lane)
        if (w < 4) {
            const float* g = zbase + (size_t)(c0 + w * 4 + (lane >> 4)) * 1024 + (lane & 15) * 4;
            gl_lds16(g, zsb + w * 256);
        }
    };

    stage(0);

    int t = 0;
#pragma unroll 1
    for (int pass = 0; pass < 8; ++pass) {
        float acc[128];
#pragma unroll
        for (int x = 0; x < 128; ++x) acc[x] = 0.0f;

#pragma unroll 1
        for (int chunk = 0; chunk < 16; ++chunk, ++t) {
            __syncthreads();                 // drains staging for buf t&1
            if (t + 1 < 128) stage(t + 1);
            const float* eb = es + (size_t)(t & 1) * ES_BUF + kg * 4;
            const float* zb = zs + (size_t)(t & 1) * ZS_BUF + ng * 8;
#pragma unroll
            for (int c = 0; c < 16; ++c) {
                const float4 za = *(const float4*)(zb + c * 64);
                const float4 zb4 = *(const float4*)(zb + c * 64 + 4);
                const float4 e0 = *(const float4*)(eb + c * 1024);
                const float4 e1 = *(const float4*)(eb + c * 1024 + 256);
                const float4 e2 = *(const float4*)(eb + c * 1024 + 512);
                const float4 e3 = *(const float4*)(eb + c * 1024 + 768);
                const float zv[8] = {za.x, za.y, za.z, za.w, zb4.x, zb4.y, zb4.z, zb4.w};
                const float ev[16] = {e0.x, e0.y, e0.z, e0.w, e1.x, e1.y, e1.z, e1.w,
                                      e2.x, e2.y, e2.z, e2.w, e3.x, e3.y, e3.z, e3.w};
#pragma unroll
                for (int i = 0; i < 8; ++i)
#pragma unroll
                    for (int j = 0; j < 16; ++j)
                        acc[i * 16 + j] = fmaf(zv[i], ev[j], acc[i * 16 + j]);
            }
        }

        // epilogue for this pass: d = (zn + en) - 2*dot, ascending k
        const int k0b = pass * 1024 + kg * 16;
        const float4 n0 = *(const float4*)(enorm + k0b);
        const float4 n1 = *(const float4*)(enorm + k0b + 4);
        const float4 n2 = *(const float4*)(enorm + k0b + 8);
        const float4 n3 = *(const float4*)(enorm + k0b + 12);
        const float en[16] = {n0.x, n0.y, n0.z, n0.w, n1.x, n1.y, n1.z, n1.w,
                              n2.x, n2.y, n2.z, n2.w, n3.x, n3.y, n3.z, n3.w};
#pragma unroll
        for (int i = 0; i < 8; ++i) {
#pragma unroll
            for (int j = 0; j < 16; ++j) {
                const float tt = zn[i] + en[j];
                const float d = tt - (acc[i * 16 + j] + acc[i * 16 + j]);
                if (d < bv[i]) { bv[i] = d; bi[i] = k0b + j; }
            }
        }
    }

    // cross-thread argmin reduce (reuse es buf0: 16 KB v + 16 KB i)
    __syncthreads();
    float* redv = es;
    int*   redi = (int*)(es + 4096);
#pragma unroll
    for (int i = 0; i < 8; ++i) {
        redv[kg * 64 + ng * 8 + i] = bv[i];
        redi[kg * 64 + ng * 8 + i] = bi[i];
    }
    __syncthreads();
    if (tid < 64) {
        float v = redv[tid];
        int   ib = redi[tid];
#pragma unroll 8
        for (int g = 1; g < 64; ++g) {
            float v2 = redv[g * 64 + tid];
            int   i2 = redi[g * 64 + tid];
            if (v2 < v || (v2 == v && i2 < ib)) { v = v2; ib = i2; }
        }
        idx_out[nb + tid] = (float)ib;
    }
}

// ---------------- K3: gather z_q (BCHW) + loss partials ----------------
__global__ void k_gather(const float* __restrict__ z, const float* __restrict__ emb,
                         const float* __restrict__ idxf, float* __restrict__ out,
                         float* __restrict__ lossAcc) {
    __shared__ float red[256];
    const int bid = blockIdx.x;
    const int b = bid >> 5, h = bid & 31;
    const int t = threadIdx.x;
    const int w_ = t & 31, cg = t >> 5;
    const int n = b * 1024 + h * 32 + w_;
    const int ki = (int)idxf[n];
    const float* ep = emb + (size_t)ki * CC;
    const size_t base = (size_t)b * 262144 + h * 32 + w_;
    float ls = 0.0f;
#pragma unroll 4
    for (int c = cg; c < CC; c += 8) {
        float e = ep[c];
        size_t a = base + (size_t)c * 1024;
        float zv = z[a];
        out[a] = e;
        float df = e - zv;
        ls = fmaf(df, df, ls);
    }
    red[t] = ls;
    __syncthreads();
    for (int s = 128; s > 0; s >>= 1) {
        if (t < s) red[t] += red[t + s];
        __syncthreads();
    }
    if (t == 0) atomicAdd(lossAcc, red[0]);
}

// ---------------- K4: finalize loss ----------------
__global__ void k_loss(const float* __restrict__ lossAcc, float* __restrict__ outLoss) {
    if (threadIdx.x == 0) {
        float m = lossAcc[0] * (1.0f / 4194304.0f);
        outLoss[0] = m + 0.25f * m;
    }
}

extern "C" void kernel_launch(void* const* d_in, const int* in_sizes, int n_in,
                              void* d_out, int out_size, void* d_ws, size_t ws_size,
                              hipStream_t stream) {
    const float* z   = (const float*)d_in[0];
    const float* emb = (const float*)d_in[1];
    float* outf = (float*)d_out;
    float* wsf  = (float*)d_ws;

    float* lossAcc = wsf;
    float* znorm   = wsf + WS_ZNORM;
    float* enorm   = wsf + WS_ENORM;
    float* eT      = wsf + WS_ET;

    k_znorm<<<64, 256, 0, stream>>>(z, znorm, lossAcc);
    k_transpose<<<dim3(128, 4), 256, 0, stream>>>(emb, eT);
    k_enorm<<<2048, 256, 0, stream>>>(emb, enorm);
    k_argmin<<<256, 512, 0, stream>>>(z, eT, znorm, enorm, outf + Z_OUT);
    k_gather<<<512, 256, 0, stream>>>(z, emb, outf + Z_OUT, outf, lossAcc);
    k_loss<<<1, 64, 0, stream>>>(lossAcc, outf + Z_OUT + NPTS);
}

// Round 4
// 891.166 us; speedup vs baseline: 4.7811x; 4.7811x over previous
//
#include <hip/hip_runtime.h>
#include <math.h>

// Problem constants
#define NB   16
#define CC   256
#define NPTS 16384       // 16*32*32
#define KK   8192
#define Z_OUT 4194304    // NPTS*CC
// d_out: [0,Z_OUT) z_q_out (BCHW), [Z_OUT,Z_OUT+NPTS) idx as float, [Z_OUT+NPTS] loss

// ws layout (floats)
#define WS_ZNORM 64
#define WS_ENORM 16448
#define WS_ET    32768          // eT[c][k], 8 MB
#define WS_CAND  2129920        // candV float[2*16384]; candI int[2*16384] right after

__device__ __forceinline__ void gl_lds16(const float* g, float* l) {
    __builtin_amdgcn_global_load_lds((const __attribute__((address_space(1))) void*)g,
                                     (__attribute__((address_space(3))) void*)l, 16, 0, 0);
}

// ---------------- K0a: znorm + zero loss accumulator ----------------
__global__ void k_znorm(const float* __restrict__ z, float* __restrict__ znorm,
                        float* __restrict__ lossAcc) {
    const int n  = blockIdx.x * 256 + threadIdx.x;
    const int b  = n >> 10, hw = n & 1023;
    const float* p = z + (size_t)b * 262144 + hw;
    float s = 0.0f;
#pragma unroll 8
    for (int c = 0; c < CC; ++c) {
        float v = p[(size_t)c * 1024];
        s = fmaf(v, v, s);
    }
    znorm[n] = s;
    if (n == 0) lossAcc[0] = 0.0f;
}

// ---------------- K0b: transpose emb[k][c] -> eT[c][k] ----------------
__global__ void k_transpose(const float* __restrict__ emb, float* __restrict__ eT) {
    __shared__ float ts[64][65];
    const int k0 = blockIdx.x * 64;
    const int c0 = blockIdx.y * 64;
    const int tid = threadIdx.x;
#pragma unroll
    for (int p = 0; p < 4; ++p) {
        int u = p * 256 + tid;
        int i = u >> 4, j4 = (u & 15) << 2;
        float4 v = *(const float4*)(emb + (size_t)(k0 + i) * CC + c0 + j4);
        ts[i][j4 + 0] = v.x; ts[i][j4 + 1] = v.y; ts[i][j4 + 2] = v.z; ts[i][j4 + 3] = v.w;
    }
    __syncthreads();
#pragma unroll
    for (int p = 0; p < 4; ++p) {
        int u = p * 256 + tid;
        int j = u >> 4, i4 = (u & 15) << 2;
        float4 v = make_float4(ts[i4 + 0][j], ts[i4 + 1][j], ts[i4 + 2][j], ts[i4 + 3][j]);
        *(float4*)(eT + (size_t)(c0 + j) * KK + k0 + i4) = v;
    }
}

// ---------------- K0c: enorm ----------------
__global__ void k_enorm(const float* __restrict__ emb, float* __restrict__ enorm) {
    const int w = threadIdx.x >> 6, lane = threadIdx.x & 63;
    const int k = blockIdx.x * 4 + w;
    float4 v = *(const float4*)(emb + (size_t)k * CC + lane * 4);
    float s = v.x * v.x + v.y * v.y + v.z * v.z + v.w * v.w;
    for (int off = 32; off > 0; off >>= 1) s += __shfl_down(s, off);
    if (lane == 0) enorm[k] = s;
}

// ---------------- K1: fused GEMM-distance + argmin ----------------
// 512 blocks x 512 threads. Block = 64 n x 4096 k (half = bid&1 picks k-half).
// Thread tile 8n x 8k -> acc[64] (fits 128-VGPR budget, no spill).
// k-strips of 512 (8 per block); c-chunks of 16, double-buffered LDS (72 KB -> 2 blk/CU).
// es[c][k'] contiguous (k'=0..511); zs[c][m] (m=0..63).
#define ES_BUF 8192    // floats per es buffer (32 KB)
#define ZS_BUF 1024    // floats per zs buffer (4 KB)

__global__ __launch_bounds__(512)
void k_argmin(const float* __restrict__ z, const float* __restrict__ eT,
              const float* __restrict__ znorm, const float* __restrict__ enorm,
              float* __restrict__ candV, int* __restrict__ candI) {
    __shared__ float es[2 * ES_BUF];   // 64 KB
    __shared__ float zs[2 * ZS_BUF];   // 8 KB
    const int tid  = threadIdx.x;
    const int lane = tid & 63;
    const int w    = tid >> 6;         // wave 0..7
    const int kg   = tid >> 3;         // 0..63 (8 k's each within strip)
    const int ng   = tid & 7;          // 0..7  (8 n's each)
    const int bid  = blockIdx.x;
    const int grp  = bid >> 1;         // n-group 0..255
    const int half = bid & 1;          // k-half
    const int nb   = grp << 6;
    const int khalf = half * 4096;
    const float* zbase = z + (size_t)(nb >> 10) * 262144 + (nb & 1023);

    float bv[8]; int bi[8];
#pragma unroll
    for (int i = 0; i < 8; ++i) { bv[i] = __builtin_inff(); bi[i] = 0; }

    // stage chunk ti (0..127) into buf ti&1
    auto stage = [&](int ti) {
        const int strip = ti >> 4, c0 = (ti & 15) << 4;
        const int k0 = khalf + strip * 512;
        float* esb = es + (size_t)(ti & 1) * ES_BUF;
        float* zsb = zs + (size_t)(ti & 1) * ZS_BUF;
        // e: wave w stages chunk-local c rows 2w, 2w+1 (2 insts each, contiguous k)
#pragma unroll
        for (int r = 0; r < 2; ++r) {
            const int c = 2 * w + r;
            const float* row = eT + (size_t)(c0 + c) * KK + k0;
            gl_lds16(row + lane * 4,       esb + c * 512);
            gl_lds16(row + 256 + lane * 4, esb + c * 512 + 256);
        }
        // z: waves 0..3 stage 4 c-rows each (64 n x 4B = 256B per row)
        if (w < 4) {
            const float* g = zbase + (size_t)(c0 + w * 4 + (lane >> 4)) * 1024 + (lane & 15) * 4;
            gl_lds16(g, zsb + w * 256);
        }
    };

    stage(0);

    int t = 0;
#pragma unroll 1
    for (int strip = 0; strip < 8; ++strip) {
        float acc[64];
#pragma unroll
        for (int x = 0; x < 64; ++x) acc[x] = 0.0f;

#pragma unroll 1
        for (int chunk = 0; chunk < 16; ++chunk, ++t) {
            __syncthreads();                 // staging of buf t&1 drained
            if (t + 1 < 128) stage(t + 1);
            const float* eb = es + (size_t)(t & 1) * ES_BUF + kg * 8;
            const float* zb = zs + (size_t)(t & 1) * ZS_BUF + ng * 8;
#pragma unroll
            for (int c = 0; c < 16; ++c) {
                const float4 z0 = *(const float4*)(zb + c * 64);
                const float4 z1 = *(const float4*)(zb + c * 64 + 4);
                const float4 e0 = *(const float4*)(eb + c * 512);
                const float4 e1 = *(const float4*)(eb + c * 512 + 4);
                const float zv[8] = {z0.x, z0.y, z0.z, z0.w, z1.x, z1.y, z1.z, z1.w};
                const float ev[8] = {e0.x, e0.y, e0.z, e0.w, e1.x, e1.y, e1.z, e1.w};
#pragma unroll
                for (int i = 0; i < 8; ++i)
#pragma unroll
                    for (int j = 0; j < 8; ++j)
                        acc[i * 8 + j] = fmaf(zv[i], ev[j], acc[i * 8 + j]);
            }
        }

        // strip epilogue: d = (zn + en) - 2*dot, k ascending
        const int k0b = khalf + strip * 512 + kg * 8;
        const float4 n0 = *(const float4*)(enorm + k0b);
        const float4 n1 = *(const float4*)(enorm + k0b + 4);
        const float en[8] = {n0.x, n0.y, n0.z, n0.w, n1.x, n1.y, n1.z, n1.w};
        const float4 a0 = *(const float4*)(znorm + nb + ng * 8);
        const float4 a1 = *(const float4*)(znorm + nb + ng * 8 + 4);
        const float zn[8] = {a0.x, a0.y, a0.z, a0.w, a1.x, a1.y, a1.z, a1.w};
#pragma unroll
        for (int i = 0; i < 8; ++i) {
#pragma unroll
            for (int j = 0; j < 8; ++j) {
                const float tt = zn[i] + en[j];
                const float d = tt - (acc[i * 8 + j] + acc[i * 8 + j]);
                if (d < bv[i]) { bv[i] = d; bi[i] = k0b + j; }
            }
        }
    }

    // cross-thread argmin reduce (reuse es: 16 KB v + 16 KB i)
    __syncthreads();
    float* redv = es;
    int*   redi = (int*)(es + 4096);
#pragma unroll
    for (int i = 0; i < 8; ++i) {
        redv[kg * 64 + ng * 8 + i] = bv[i];
        redi[kg * 64 + ng * 8 + i] = bi[i];
    }
    __syncthreads();
    if (tid < 64) {
        float v = redv[tid];
        int   ib = redi[tid];
#pragma unroll 8
        for (int g = 1; g < 64; ++g) {
            float v2 = redv[g * 64 + tid];
            int   i2 = redi[g * 64 + tid];
            if (v2 < v || (v2 == v && i2 < ib)) { v = v2; ib = i2; }
        }
        candV[half * NPTS + nb + tid] = v;
        candI[half * NPTS + nb + tid] = ib;
    }
}

// ---------------- K2: merge k-halves ----------------
__global__ void k_pick(const float* __restrict__ candV, const int* __restrict__ candI,
                       float* __restrict__ idx_out) {
    const int n = blockIdx.x * 256 + threadIdx.x;   // 64 blocks
    const float v0 = candV[n], v1 = candV[NPTS + n];
    const int   i0 = candI[n], i1 = candI[NPTS + n];
    // half0 indices < half1 indices, so ties (v1==v0) keep i0
    idx_out[n] = (float)((v1 < v0) ? i1 : i0);
}

// ---------------- K3: gather z_q (BCHW) + loss partials ----------------
__global__ void k_gather(const float* __restrict__ z, const float* __restrict__ emb,
                         const float* __restrict__ idxf, float* __restrict__ out,
                         float* __restrict__ lossAcc) {
    __shared__ float red[256];
    const int bid = blockIdx.x;
    const int b = bid >> 5, h = bid & 31;
    const int t = threadIdx.x;
    const int w_ = t & 31, cg = t >> 5;
    const int n = b * 1024 + h * 32 + w_;
    const int ki = (int)idxf[n];
    const float* ep = emb + (size_t)ki * CC;
    const size_t base = (size_t)b * 262144 + h * 32 + w_;
    float ls = 0.0f;
#pragma unroll 4
    for (int c = cg; c < CC; c += 8) {
        float e = ep[c];
        size_t a = base + (size_t)c * 1024;
        float zv = z[a];
        out[a] = e;
        float df = e - zv;
        ls = fmaf(df, df, ls);
    }
    red[t] = ls;
    __syncthreads();
    for (int s = 128; s > 0; s >>= 1) {
        if (t < s) red[t] += red[t + s];
        __syncthreads();
    }
    if (t == 0) atomicAdd(lossAcc, red[0]);
}

// ---------------- K4: finalize loss ----------------
__global__ void k_loss(const float* __restrict__ lossAcc, float* __restrict__ outLoss) {
    if (threadIdx.x == 0) {
        float m = lossAcc[0] * (1.0f / 4194304.0f);
        outLoss[0] = m + 0.25f * m;
    }
}

extern "C" void kernel_launch(void* const* d_in, const int* in_sizes, int n_in,
                              void* d_out, int out_size, void* d_ws, size_t ws_size,
                              hipStream_t stream) {
    const float* z   = (const float*)d_in[0];
    const float* emb = (const float*)d_in[1];
    float* outf = (float*)d_out;
    float* wsf  = (float*)d_ws;

    float* lossAcc = wsf;
    float* znorm   = wsf + WS_ZNORM;
    float* enorm   = wsf + WS_ENORM;
    float* eT      = wsf + WS_ET;
    float* candV   = wsf + WS_CAND;
    int*   candI   = (int*)(wsf + WS_CAND + 2 * NPTS);

    k_znorm<<<64, 256, 0, stream>>>(z, znorm, lossAcc);
    k_transpose<<<dim3(128, 4), 256, 0, stream>>>(emb, eT);
    k_enorm<<<2048, 256, 0, stream>>>(emb, enorm);
    k_argmin<<<512, 512, 0, stream>>>(z, eT, znorm, enorm, candV, candI);
    k_pick<<<64, 256, 0, stream>>>(candV, candI, outf + Z_OUT);
    k_gather<<<512, 256, 0, stream>>>(z, emb, outf + Z_OUT, outf, lossAcc);
    k_loss<<<1, 64, 0, stream>>>(lossAcc, outf + Z_OUT + NPTS);
}

// Round 5
// 624.767 us; speedup vs baseline: 6.8198x; 1.4264x over previous
//
#include <hip/hip_runtime.h>
#include <math.h>

// Problem constants
#define NB   16
#define CC   256
#define NPTS 16384       // 16*32*32
#define KK   8192
#define Z_OUT 4194304    // NPTS*CC
// d_out: [0,Z_OUT) z_q_out (BCHW), [Z_OUT,Z_OUT+NPTS) idx as float, [Z_OUT+NPTS] loss
// d_out scratch reuse (before k_gather overwrites): zb16 = bf16[16384][256] at slot 0
// (2,097,152 float-slots), ebf = bf16[8192][256] at slot 2,097,152 (1,048,576 slots).

// ws layout (floats)
#define WS_ZNORM 64
#define WS_ENORM 16448
#define WS_CCNT  24640                // int[16384] candidate counts
#define WS_CIDX  41024                // int[16384][64] candidate k lists
#define CAND_CAP 64
#define MARGIN   4.0e-4f              // > 2*eps_bf16 + d-quantum + enorm spread

typedef short v8s __attribute__((ext_vector_type(8)));
typedef float v4f __attribute__((ext_vector_type(4)));

__device__ __forceinline__ void gl_lds16(const void* g, void* l) {
    __builtin_amdgcn_global_load_lds((const __attribute__((address_space(1))) void*)g,
                                     (__attribute__((address_space(3))) void*)l, 16, 0, 0);
}
__device__ __forceinline__ unsigned short f2bf(float f) {   // RNE, finite inputs
    unsigned int u = __float_as_uint(f);
    return (unsigned short)((u + 0x7FFFu + ((u >> 16) & 1u)) >> 16);
}

// ---------------- P0: z BCHW fp32 -> zb16[n][c] bf16 (transpose+cast) ----------------
__global__ void k_prep_z(const float* __restrict__ z, unsigned short* __restrict__ zb16) {
    __shared__ float ts[64][65];
    const int hw0 = blockIdx.x * 64, c0 = blockIdx.y * 64, b = blockIdx.z;
    const int tid = threadIdx.x;
#pragma unroll
    for (int p = 0; p < 4; ++p) {
        int u = p * 256 + tid;
        int ci = u >> 4, j4 = (u & 15) << 2;
        float4 v = *(const float4*)(z + (size_t)b * 262144 + (size_t)(c0 + ci) * 1024 + hw0 + j4);
        ts[ci][j4 + 0] = v.x; ts[ci][j4 + 1] = v.y; ts[ci][j4 + 2] = v.z; ts[ci][j4 + 3] = v.w;
    }
    __syncthreads();
#pragma unroll
    for (int p = 0; p < 4; ++p) {
        int u = p * 256 + tid;
        int hj = u >> 4, i4 = (u & 15) << 2;
        ushort4 o = make_ushort4(f2bf(ts[i4 + 0][hj]), f2bf(ts[i4 + 1][hj]),
                                 f2bf(ts[i4 + 2][hj]), f2bf(ts[i4 + 3][hj]));
        *(ushort4*)(zb16 + (size_t)(b * 1024 + hw0 + hj) * 256 + c0 + i4) = o;
    }
}

// ---------------- P1: emb fp32 -> ebf[k][c] bf16 ----------------
__global__ void k_prep_e(const float* __restrict__ emb, unsigned short* __restrict__ ebf) {
    const int i = (blockIdx.x * 256 + threadIdx.x) * 8;
    float4 a = *(const float4*)(emb + i);
    float4 b = *(const float4*)(emb + i + 4);
    *(ushort4*)(ebf + i)     = make_ushort4(f2bf(a.x), f2bf(a.y), f2bf(a.z), f2bf(a.w));
    *(ushort4*)(ebf + i + 4) = make_ushort4(f2bf(b.x), f2bf(b.y), f2bf(b.z), f2bf(b.w));
}

// ---------------- znorm + zero loss ----------------
__global__ void k_znorm(const float* __restrict__ z, float* __restrict__ znorm,
                        float* __restrict__ lossAcc) {
    const int n  = blockIdx.x * 256 + threadIdx.x;
    const int b  = n >> 10, hw = n & 1023;
    const float* p = z + (size_t)b * 262144 + hw;
    float s = 0.0f;
#pragma unroll 8
    for (int c = 0; c < CC; ++c) {
        float v = p[(size_t)c * 1024];
        s = fmaf(v, v, s);
    }
    znorm[n] = s;
    if (n == 0) lossAcc[0] = 0.0f;
}

// ---------------- enorm ----------------
__global__ void k_enorm(const float* __restrict__ emb, float* __restrict__ enorm) {
    const int w = threadIdx.x >> 6, lane = threadIdx.x & 63;
    const int k = blockIdx.x * 4 + w;
    float4 v = *(const float4*)(emb + (size_t)k * CC + lane * 4);
    float s = v.x * v.x + v.y * v.y + v.z * v.z + v.w * v.w;
    for (int off = 32; off > 0; off >>= 1) s += __shfl_down(s, off);
    if (lane == 0) enorm[k] = s;
}

// ---------------- Phase 1: bf16 MFMA dot + online max + candidate collection ----------
// 256 blocks x 512 thr (8 waves). Block = 64 n, full 8192 k. Wave w owns k in
// [w*1024,(w+1)*1024), processed in 16 iters of 64k; c in 8 chunks of 32 (dbuf LDS).
// Staging in fragment order: lane's 16B = its MFMA fragment; ds_read_b128 @ lane*16.
// mfma_f32_16x16x32_bf16: A[m=lane&15][c=(lane>>4)*8+j]; B[c][n=lane&15];
// D: col(n)=lane&15, row(k)=(lane>>4)*4+reg.
__global__ __launch_bounds__(512)
void k_phase1(const unsigned short* __restrict__ zb16, const unsigned short* __restrict__ ebf,
              int* __restrict__ candCnt, int* __restrict__ candI) {
    __shared__ short As[2][8][4][512];   // 64 KB  [buf][wave][ktile][lane*8]
    __shared__ short Bs[2][4][512];      // 8 KB   [buf][ntile][lane*8]
    __shared__ float runmax[64];
    __shared__ float wavemax[8][64];
    __shared__ int   cnt[64];
    __shared__ int   lst[64][CAND_CAP];  // 16 KB

    const int tid  = threadIdx.x;
    const int lane = tid & 63;
    const int w    = tid >> 6;
    const int nb   = blockIdx.x << 6;
    const int m16  = lane & 15, q = lane >> 4;

    if (tid < 64) { runmax[tid] = -__builtin_inff(); cnt[tid] = 0; }

    auto stage = [&](int t) {
        const int s = t >> 3, c0 = (t & 7) << 5, buf = t & 1;
        const int kbase = (w << 10) + (s << 6);
#pragma unroll
        for (int kt = 0; kt < 4; ++kt) {
            const unsigned short* g = ebf + (size_t)(kbase + (kt << 4) + m16) * 256 + c0 + q * 8;
            gl_lds16(g, &As[buf][w][kt][lane * 8]);
        }
        if (w < 4) {
            const unsigned short* g = zb16 + (size_t)(nb + (w << 4) + m16) * 256 + c0 + q * 8;
            gl_lds16(g, &Bs[buf][w][lane * 8]);
        }
    };

    stage(0);

    v4f acc[16];
#pragma unroll
    for (int i = 0; i < 16; ++i) acc[i] = (v4f){0.f, 0.f, 0.f, 0.f};

#pragma unroll 1
    for (int t = 0; t < 128; ++t) {
        __syncthreads();
        if (t + 1 < 128) stage(t + 1);
        const int buf = t & 1;
        v8s af[4], bf[4];
#pragma unroll
        for (int kt = 0; kt < 4; ++kt) af[kt] = *(const v8s*)&As[buf][w][kt][lane * 8];
#pragma unroll
        for (int nt = 0; nt < 4; ++nt) bf[nt] = *(const v8s*)&Bs[buf][nt][lane * 8];
#pragma unroll
        for (int kt = 0; kt < 4; ++kt)
#pragma unroll
            for (int nt = 0; nt < 4; ++nt)
                acc[kt * 4 + nt] = __builtin_amdgcn_mfma_f32_16x16x32_bf16(
                    af[kt], bf[nt], acc[kt * 4 + nt], 0, 0, 0);

        if ((t & 7) == 7) {   // end of 64k iter s: reduce max, push candidates
            const int s = t >> 3;
            // per-lane max per ntile, then across the 4 lanes sharing n
#pragma unroll
            for (int nt = 0; nt < 4; ++nt) {
                float m = acc[nt][0];
#pragma unroll
                for (int kt = 0; kt < 4; ++kt)
#pragma unroll
                    for (int r = 0; r < 4; ++r) m = fmaxf(m, acc[kt * 4 + nt][r]);
                m = fmaxf(m, __shfl_xor(m, 16));
                m = fmaxf(m, __shfl_xor(m, 32));
                if (lane < 16) wavemax[w][nt * 16 + lane] = m;
            }
            __syncthreads();
            if (tid < 64) {
                float r = runmax[tid];
#pragma unroll
                for (int ww = 0; ww < 8; ++ww) r = fmaxf(r, wavemax[ww][tid]);
                runmax[tid] = r;
            }
            __syncthreads();
#pragma unroll
            for (int nt = 0; nt < 4; ++nt) {
                const int nl = nt * 16 + m16;
                const float thr = runmax[nl] - MARGIN;
#pragma unroll
                for (int kt = 0; kt < 4; ++kt)
#pragma unroll
                    for (int r = 0; r < 4; ++r) {
                        if (acc[kt * 4 + nt][r] >= thr) {
                            int k = (w << 10) + (s << 6) + (kt << 4) + q * 4 + r;
                            int pos = atomicAdd(&cnt[nl], 1);
                            if (pos < CAND_CAP) lst[nl][pos] = k;
                        }
                    }
            }
#pragma unroll
            for (int i = 0; i < 16; ++i) acc[i] = (v4f){0.f, 0.f, 0.f, 0.f};
        }
    }

    __syncthreads();
    if (tid < 64) {
        const int n = nb + tid;
        const int c = cnt[tid];
        candCnt[n] = c;
        const int m = c < CAND_CAP ? c : CAND_CAP;
        for (int i = 0; i < m; ++i) candI[(size_t)n * CAND_CAP + i] = lst[tid][i];
    }
}

// ---------------- Phase 2: exact fp32 rescore (chain identical to round-4 kernel) ----
__global__ void k_rescore(const float* __restrict__ z, const float* __restrict__ emb,
                          const float* __restrict__ znorm, const float* __restrict__ enorm,
                          const int* __restrict__ candCnt, const int* __restrict__ candI,
                          float* __restrict__ idx_out) {
    const int lane = threadIdx.x & 63;
    const int gw   = blockIdx.x * 4 + (threadIdx.x >> 6);   // 1024 waves, 16 rows each
#pragma unroll 1
    for (int rr = 0; rr < 16; ++rr) {
        const int n = gw * 16 + rr;
        const int b = n >> 10, hw = n & 1023;
        const float* zp = z + (size_t)b * 262144 + hw;
        const float zn = znorm[n];
        const int cnt = candCnt[n];
        float bd = __builtin_inff();
        int   bk = 0x7fffffff;
        if (cnt <= CAND_CAP) {
            if (lane < cnt) {
                const int k = candI[(size_t)n * CAND_CAP + lane];
                const float* ep = emb + (size_t)k * CC;
                float acc = 0.0f;
#pragma unroll 4
                for (int c = 0; c < CC; ++c) acc = fmaf(zp[(size_t)c * 1024], ep[c], acc);
                const float tt = zn + enorm[k];
                bd = tt - (acc + acc);
                bk = k;
            }
        } else {
            // overflow fallback: exact full scan (same chain), lane-strided k
#pragma unroll 1
            for (int kb = 0; kb < 128; ++kb) {
                const int k = kb * 64 + lane;
                const float* ep = emb + (size_t)k * CC;
                float acc = 0.0f;
#pragma unroll 4
                for (int c = 0; c < CC; ++c) acc = fmaf(zp[(size_t)c * 1024], ep[c], acc);
                const float tt = zn + enorm[k];
                const float d = tt - (acc + acc);
                if (d < bd) { bd = d; bk = k; }   // ascending k per lane
            }
        }
        // cross-lane min with smaller-k tie-break
#pragma unroll
        for (int off = 32; off > 0; off >>= 1) {
            const float od = __shfl_down(bd, off);
            const int   ok = __shfl_down(bk, off);
            if (od < bd || (od == bd && ok < bk)) { bd = od; bk = ok; }
        }
        if (lane == 0) idx_out[n] = (float)bk;
    }
}

// ---------------- gather z_q (BCHW) + loss partials ----------------
__global__ void k_gather(const float* __restrict__ z, const float* __restrict__ emb,
                         const float* __restrict__ idxf, float* __restrict__ out,
                         float* __restrict__ lossAcc) {
    __shared__ float red[256];
    const int bid = blockIdx.x;
    const int b = bid >> 5, h = bid & 31;
    const int t = threadIdx.x;
    const int w_ = t & 31, cg = t >> 5;
    const int n = b * 1024 + h * 32 + w_;
    const int ki = (int)idxf[n];
    const float* ep = emb + (size_t)ki * CC;
    const size_t base = (size_t)b * 262144 + h * 32 + w_;
    float ls = 0.0f;
#pragma unroll 4
    for (int c = cg; c < CC; c += 8) {
        float e = ep[c];
        size_t a = base + (size_t)c * 1024;
        float zv = z[a];
        out[a] = e;
        float df = e - zv;
        ls = fmaf(df, df, ls);
    }
    red[t] = ls;
    __syncthreads();
    for (int s = 128; s > 0; s >>= 1) {
        if (t < s) red[t] += red[t + s];
        __syncthreads();
    }
    if (t == 0) atomicAdd(lossAcc, red[0]);
}

// ---------------- finalize loss ----------------
__global__ void k_loss(const float* __restrict__ lossAcc, float* __restrict__ outLoss) {
    if (threadIdx.x == 0) {
        float m = lossAcc[0] * (1.0f / 4194304.0f);
        outLoss[0] = m + 0.25f * m;
    }
}

extern "C" void kernel_launch(void* const* d_in, const int* in_sizes, int n_in,
                              void* d_out, int out_size, void* d_ws, size_t ws_size,
                              hipStream_t stream) {
    const float* z   = (const float*)d_in[0];
    const float* emb = (const float*)d_in[1];
    float* outf = (float*)d_out;
    float* wsf  = (float*)d_ws;

    float* lossAcc = wsf;
    float* znorm   = wsf + WS_ZNORM;
    float* enorm   = wsf + WS_ENORM;
    int*   candCnt = (int*)(wsf + WS_CCNT);
    int*   candI   = (int*)(wsf + WS_CIDX);

    // d_out z_q region doubles as bf16 scratch until k_gather overwrites it
    unsigned short* zb16 = (unsigned short*)outf;                  // 8 MB
    unsigned short* ebf  = (unsigned short*)(outf + 2097152);      // 4 MB

    k_prep_z<<<dim3(16, 4, 16), 256, 0, stream>>>(z, zb16);
    k_prep_e<<<1024, 256, 0, stream>>>(emb, ebf);
    k_znorm<<<64, 256, 0, stream>>>(z, znorm, lossAcc);
    k_enorm<<<2048, 256, 0, stream>>>(emb, enorm);
    k_phase1<<<256, 512, 0, stream>>>(zb16, ebf, candCnt, candI);
    k_rescore<<<256, 256, 0, stream>>>(z, emb, znorm, enorm, candCnt, candI, outf + Z_OUT);
    k_gather<<<512, 256, 0, stream>>>(z, emb, outf + Z_OUT, outf, lossAcc);
    k_loss<<<1, 64, 0, stream>>>(lossAcc, outf + Z_OUT + NPTS);
}